// Round 1
// baseline (134.747 us; speedup 1.0000x reference)
//
#include <hip/hip_runtime.h>
#include <stdint.h>

// BlockAttention: B=8, S=8192, D=H=128, BLOCK=256, WINDOW=256 (halo 255, W=766)
// No softmax => out_blk = Q_blk @ (scale * K_win^T V_win)  -- linear attention trick.
// M_n = K_win^T V_win is 128x128 per (b,block); 3x fewer FLOPs than direct QK^T,PV.
//
// proj_kernel: x(f32) -> q bf16 [b][s][d], kt bf16 [b][d][s], vt bf16 [b][h][s] (ws)
// attn_kernel: per (b,n): M^T[h][d] = sum_s vt[h][s]*kt[d][s] over masked window,
//              then O = Q * M with M^T staged in LDS. MFMA 32x32x16 bf16 throughout.

#define B_ 8
#define S_ 8192

using bf16x8 = __attribute__((ext_vector_type(8))) short;   // 8 bf16 = 4 VGPRs
using s16x4  = __attribute__((ext_vector_type(4))) short;
using f32x16 = __attribute__((ext_vector_type(16))) float;

__device__ __forceinline__ short f2bf(float f) {
  union { float f; uint32_t u; } v; v.f = f;
  uint32_t r = v.u + 0x7fffu + ((v.u >> 16) & 1u);   // RNE
  return (short)(r >> 16);
}

// ---------------------------------------------------------------------------
// Projection: 512 blocks x 256 threads, 128 rows (b*S+s) per block.
// Wave w owns rows [32w, 32w+32). A-frags (x rows, bf16) live in registers and
// are reused for all three weights. W staged to LDS per output. k/v outputs are
// transposed through the same LDS buffer for coalesced [d][s] global stores.
// ---------------------------------------------------------------------------
#define LDW 136   // padded leading dim (bf16 elems) for 128-wide LDS tiles

__global__ __launch_bounds__(256) void proj_kernel(
    const float* __restrict__ x,
    const float* __restrict__ Wq, const float* __restrict__ bq,
    const float* __restrict__ Wk, const float* __restrict__ bk,
    const float* __restrict__ Wv, const float* __restrict__ bv,
    short* __restrict__ qb, short* __restrict__ ktb, short* __restrict__ vtb)
{
  __shared__ short wl[128 * LDW];   // 34.8 KB: weight tile, then transpose tile

  const int tid  = threadIdx.x;
  const int lane = tid & 63;
  const int wv   = tid >> 6;
  const int c    = lane & 31;      // MFMA row/col index within 32-tile
  const int hl   = lane >> 5;      // half-wave (k-subchunk select)
  const int r0   = blockIdx.x * 128;
  const int b    = r0 >> 13;       // /8192
  const int s0   = r0 & (S_ - 1);

  // A fragments: A[m=lane&31][k=16*kst+8*hl+j], m-row = r0 + wv*32 + c
  bf16x8 afrag[8];
  {
    const float* xrow = x + (size_t)(r0 + wv * 32 + c) * 128 + hl * 8;
    #pragma unroll
    for (int kst = 0; kst < 8; ++kst) {
      const float4* p = (const float4*)(xrow + kst * 16);
      float4 f0 = p[0], f1 = p[1];
      bf16x8 a;
      a[0] = f2bf(f0.x); a[1] = f2bf(f0.y); a[2] = f2bf(f0.z); a[3] = f2bf(f0.w);
      a[4] = f2bf(f1.x); a[5] = f2bf(f1.y); a[6] = f2bf(f1.z); a[7] = f2bf(f1.w);
      afrag[kst] = a;
    }
  }

  auto stageW = [&](const float* W) {
    #pragma unroll
    for (int it = 0; it < 16; ++it) {
      int l  = it * 256 + tid;
      int n  = l >> 5;
      int k4 = (l & 31) << 2;
      const float4 f = *(const float4*)(W + n * 128 + k4);
      s16x4 o;
      o[0] = f2bf(f.x); o[1] = f2bf(f.y); o[2] = f2bf(f.z); o[3] = f2bf(f.w);
      *(s16x4*)(wl + n * LDW + k4) = o;
    }
  };

  auto gemm = [&](const float* bias, f32x16* acc) {
    #pragma unroll
    for (int nt = 0; nt < 4; ++nt) {
      float bvv = bias[nt * 32 + c];
      #pragma unroll
      for (int i = 0; i < 16; ++i) acc[nt][i] = bvv;
    }
    #pragma unroll
    for (int kst = 0; kst < 8; ++kst) {
      #pragma unroll
      for (int nt = 0; nt < 4; ++nt) {
        bf16x8 bb = *(const bf16x8*)(wl + (nt * 32 + c) * LDW + kst * 16 + hl * 8);
        acc[nt] = __builtin_amdgcn_mfma_f32_32x32x16_bf16(afrag[kst], bb, acc[nt], 0, 0, 0);
      }
    }
  };

  // writes C-tile (32x32 layout: col=lane&31, row=(reg&3)+8*(reg>>2)+4*hl)
  auto writeTransposedLDS = [&](f32x16* acc) {
    #pragma unroll
    for (int nt = 0; nt < 4; ++nt) {
      int d = nt * 32 + c;
      #pragma unroll
      for (int g = 0; g < 4; ++g) {
        #pragma unroll
        for (int p = 0; p < 2; ++p) {
          int reg = g * 4 + p * 2;                 // rows sl, sl+1
          int sl  = wv * 32 + g * 8 + hl * 4 + p * 2;
          uint32_t pk = (uint32_t)(uint16_t)f2bf(acc[nt][reg]) |
                        ((uint32_t)(uint16_t)f2bf(acc[nt][reg + 1]) << 16);
          *(uint32_t*)(wl + d * LDW + sl) = pk;
        }
      }
    }
  };

  auto storeTransposed = [&](short* dst) {  // dst = ktb or vtb, [b][d][s]
    #pragma unroll
    for (int it = 0; it < 8; ++it) {
      int l  = it * 256 + tid;
      int d  = l >> 4;
      int s8 = (l & 15) << 3;
      bf16x8 vv = *(const bf16x8*)(wl + d * LDW + s8);
      *(bf16x8*)(dst + ((size_t)b * 128 + d) * S_ + s0 + s8) = vv;
    }
  };

  // ---- Q ----
  stageW(Wq);
  __syncthreads();
  {
    f32x16 acc[4];
    gemm(bq, acc);
    short* qrow = qb + (size_t)r0 * 128;
    #pragma unroll
    for (int nt = 0; nt < 4; ++nt) {
      #pragma unroll
      for (int reg = 0; reg < 16; ++reg) {
        int row = (reg & 3) + 8 * (reg >> 2) + 4 * hl;
        qrow[(size_t)(wv * 32 + row) * 128 + nt * 32 + c] = f2bf(acc[nt][reg]);
      }
    }
  }
  __syncthreads();

  // ---- K (transposed out) ----
  stageW(Wk);
  __syncthreads();
  {
    f32x16 acc[4];
    gemm(bk, acc);
    __syncthreads();          // all waves done reading Wk from wl
    writeTransposedLDS(acc);
    __syncthreads();
    storeTransposed(ktb);
  }
  __syncthreads();

  // ---- V (transposed out) ----
  stageW(Wv);
  __syncthreads();
  {
    f32x16 acc[4];
    gemm(bv, acc);
    __syncthreads();
    writeTransposedLDS(acc);
    __syncthreads();
    storeTransposed(vtb);
  }
}

// ---------------------------------------------------------------------------
// Attention: 256 blocks (b,n) x 256 threads.
// Phase 1: M^T[h][d] += vt[h][s] * kt[d][s], s over 12 aligned 64-key chunks
//          [n*256-256, n*256+512); kt zero-masked outside [win_lo, win_hi).
//          Chunk skip keeps all global reads in [0, S).
// Phase 2: M^T * scale -> bf16 -> LDS (aliases chunk buffers).
// Phase 3: O[q][h] = sum_d Q[q][d] * M^T[h][d]; Q A-frags straight from global.
// ---------------------------------------------------------------------------
#define LDC 72    // chunk tile leading dim (64 s + 8 pad)
#define LDM 136

__global__ __launch_bounds__(256) void attn_kernel(
    const short* __restrict__ qb, const short* __restrict__ ktb,
    const short* __restrict__ vtb, float* __restrict__ out)
{
  __shared__ short smem[2 * 128 * LDC];   // 36.9 KB
  short* kt_c = smem;
  short* vt_c = smem + 128 * LDC;
  short* m_l  = smem;                      // alias: 128*LDM shorts = 34.8 KB fits

  const int tid  = threadIdx.x;
  const int lane = tid & 63;
  const int wv   = tid >> 6;
  const int c    = lane & 31;
  const int hl   = lane >> 5;
  const int bn   = blockIdx.x;
  const int b    = bn >> 5;
  const int n    = bn & 31;

  const int win_lo = max(n * 256 - 255, 0);
  const int win_hi = min(n * 256 + 511, S_);

  const short* ktb_b = ktb + (size_t)b * 128 * S_;
  const short* vtb_b = vtb + (size_t)b * 128 * S_;

  f32x16 macc[4];
  #pragma unroll
  for (int nt = 0; nt < 4; ++nt)
    #pragma unroll
    for (int i = 0; i < 16; ++i) macc[nt][i] = 0.f;

  for (int j = 0; j < 12; ++j) {
    int c0 = n * 256 - 256 + j * 64;
    if (c0 + 64 <= win_lo || c0 >= win_hi) continue;   // uniform over block
    __syncthreads();   // prior chunk's MFMA reads complete before restage
    #pragma unroll
    for (int it = 0; it < 4; ++it) {
      int l  = it * 256 + tid;
      int d  = l >> 3;
      int s8 = (l & 7) << 3;
      int sb = c0 + s8;
      bf16x8 kv = *(const bf16x8*)(ktb_b + (size_t)d * S_ + sb);
      if (sb < win_lo || sb + 7 >= win_hi) {
        #pragma unroll
        for (int e = 0; e < 8; ++e)
          if (sb + e < win_lo || sb + e >= win_hi) kv[e] = 0;
      }
      *(bf16x8*)(kt_c + d * LDC + s8) = kv;
      bf16x8 vv = *(const bf16x8*)(vtb_b + (size_t)d * S_ + sb);
      *(bf16x8*)(vt_c + d * LDC + s8) = vv;   // unmasked: pairs with kt zeros
    }
    __syncthreads();
    // wave wv: M^T rows h in [32wv, 32wv+32), all 128 d
    #pragma unroll
    for (int kst = 0; kst < 4; ++kst) {
      bf16x8 a = *(const bf16x8*)(vt_c + (wv * 32 + c) * LDC + kst * 16 + hl * 8);
      #pragma unroll
      for (int nt = 0; nt < 4; ++nt) {
        bf16x8 bb = *(const bf16x8*)(kt_c + (nt * 32 + c) * LDC + kst * 16 + hl * 8);
        macc[nt] = __builtin_amdgcn_mfma_f32_32x32x16_bf16(a, bb, macc[nt], 0, 0, 0);
      }
    }
  }

  __syncthreads();
  const float scale = 0.08838834764831845f;   // 1/sqrt(128), folded into M
  #pragma unroll
  for (int nt = 0; nt < 4; ++nt) {
    #pragma unroll
    for (int reg = 0; reg < 16; ++reg) {
      int row = (reg & 3) + 8 * (reg >> 2) + 4 * hl;
      m_l[(wv * 32 + row) * LDM + nt * 32 + c] = f2bf(macc[nt][reg] * scale);
    }
  }
  __syncthreads();

  // Phase 3: wave wv owns 64 q-rows [n*256 + 64wv, +64)
  f32x16 oacc[2][4];
  #pragma unroll
  for (int mt = 0; mt < 2; ++mt)
    #pragma unroll
    for (int nt = 0; nt < 4; ++nt)
      #pragma unroll
      for (int i = 0; i < 16; ++i) oacc[mt][nt][i] = 0.f;

  const short* q0p = qb + ((size_t)b * S_ + n * 256 + wv * 64 + c) * 128 + hl * 8;
  #pragma unroll
  for (int kst = 0; kst < 8; ++kst) {
    bf16x8 a0 = *(const bf16x8*)(q0p + kst * 16);
    bf16x8 a1 = *(const bf16x8*)(q0p + (size_t)32 * 128 + kst * 16);
    #pragma unroll
    for (int nt = 0; nt < 4; ++nt) {
      bf16x8 bb = *(const bf16x8*)(m_l + (nt * 32 + c) * LDM + kst * 16 + hl * 8);
      oacc[0][nt] = __builtin_amdgcn_mfma_f32_32x32x16_bf16(a0, bb, oacc[0][nt], 0, 0, 0);
      oacc[1][nt] = __builtin_amdgcn_mfma_f32_32x32x16_bf16(a1, bb, oacc[1][nt], 0, 0, 0);
    }
  }

  float* outb = out + ((size_t)b * S_ + n * 256 + wv * 64) * 128;
  #pragma unroll
  for (int mt = 0; mt < 2; ++mt) {
    #pragma unroll
    for (int nt = 0; nt < 4; ++nt) {
      #pragma unroll
      for (int reg = 0; reg < 16; ++reg) {
        int row = mt * 32 + (reg & 3) + 8 * (reg >> 2) + 4 * hl;
        outb[(size_t)row * 128 + nt * 32 + c] = oacc[mt][nt][reg];
      }
    }
  }
}

// ---------------------------------------------------------------------------
extern "C" void kernel_launch(void* const* d_in, const int* in_sizes, int n_in,
                              void* d_out, int out_size, void* d_ws, size_t ws_size,
                              hipStream_t stream) {
  const float* x  = (const float*)d_in[0];
  const float* Wq = (const float*)d_in[1];
  const float* bq = (const float*)d_in[2];
  const float* Wk = (const float*)d_in[3];
  const float* bk = (const float*)d_in[4];
  const float* Wv = (const float*)d_in[5];
  const float* bv = (const float*)d_in[6];
  float* out = (float*)d_out;

  const size_t elems = (size_t)B_ * S_ * 128;   // 8.39M bf16 per tensor
  short* qb  = (short*)d_ws;
  short* ktb = qb + elems;
  short* vtb = ktb + elems;                      // total 50.3 MB of ws

  proj_kernel<<<512, 256, 0, stream>>>(x, Wq, bq, Wk, bk, Wv, bv, qb, ktb, vtb);
  attn_kernel<<<256, 256, 0, stream>>>(qb, ktb, vtb, out);
}

// Round 3
// 123.569 us; speedup vs baseline: 1.0905x; 1.0905x over previous
//
#include <hip/hip_runtime.h>
#include <stdint.h>

// BlockAttention: B=8, S=8192, D=H=128, BLOCK=256, WINDOW=256 (halo 255, W=766)
// No softmax => out_blk = Q_blk @ (scale * K_win^T V_win)  -- linear attention trick.
//
// proj_kernel: x(f32) -> q bf16 [b][s][d], kt bf16 [b][d][s], vt bf16 [b][h][s]
// attn_kernel: per (b,n): M^T[h][d] = sum_s vt[h][s]*kt[d][s] over masked window
//              (double-buffered 64-key chunks), then O = Q * M via LDS-staged M^T.

#define B_ 8
#define S_ 8192

using bf16x8 = __attribute__((ext_vector_type(8))) short;   // 8 bf16 = 4 VGPRs
using s16x4  = __attribute__((ext_vector_type(4))) short;
using f32x16 = __attribute__((ext_vector_type(16))) float;

__device__ __forceinline__ short f2bf(float f) {
  union { float f; uint32_t u; } v; v.f = f;
  uint32_t r = v.u + 0x7fffu + ((v.u >> 16) & 1u);   // RNE
  return (short)(r >> 16);
}

// ---------------------------------------------------------------------------
// Projection: 512 blocks x 256 threads, 128 rows (b*S+s) per block.
// ---------------------------------------------------------------------------
#define LDW 136   // padded leading dim (bf16 elems) for 128-wide LDS tiles

__global__ __launch_bounds__(256) void proj_kernel(
    const float* __restrict__ x,
    const float* __restrict__ Wq, const float* __restrict__ bq,
    const float* __restrict__ Wk, const float* __restrict__ bk,
    const float* __restrict__ Wv, const float* __restrict__ bv,
    short* __restrict__ qb, short* __restrict__ ktb, short* __restrict__ vtb)
{
  __shared__ short wl[128 * LDW];   // 34.8 KB: weight tile / transpose tile

  const int tid  = threadIdx.x;
  const int lane = tid & 63;
  const int wv   = tid >> 6;
  const int c    = lane & 31;
  const int hl   = lane >> 5;
  const int r0   = blockIdx.x * 128;
  const int b    = r0 >> 13;
  const int s0   = r0 & (S_ - 1);

  // A fragments: A[m=lane&31][k=16*kst+8*hl+j], m-row = r0 + wv*32 + c
  bf16x8 afrag[8];
  {
    const float* xrow = x + (size_t)(r0 + wv * 32 + c) * 128 + hl * 8;
    #pragma unroll
    for (int kst = 0; kst < 8; ++kst) {
      const float4* p = (const float4*)(xrow + kst * 16);
      float4 f0 = p[0], f1 = p[1];
      bf16x8 a;
      a[0] = f2bf(f0.x); a[1] = f2bf(f0.y); a[2] = f2bf(f0.z); a[3] = f2bf(f0.w);
      a[4] = f2bf(f1.x); a[5] = f2bf(f1.y); a[6] = f2bf(f1.z); a[7] = f2bf(f1.w);
      afrag[kst] = a;
    }
  }

  auto stageW = [&](const float* W) {
    #pragma unroll
    for (int it = 0; it < 16; ++it) {
      int l  = it * 256 + tid;
      int n  = l >> 5;
      int k4 = (l & 31) << 2;
      const float4 f = *(const float4*)(W + n * 128 + k4);
      s16x4 o;
      o[0] = f2bf(f.x); o[1] = f2bf(f.y); o[2] = f2bf(f.z); o[3] = f2bf(f.w);
      *(s16x4*)(wl + n * LDW + k4) = o;
    }
  };

  auto gemm = [&](const float* bias, f32x16* acc) {
    #pragma unroll
    for (int nt = 0; nt < 4; ++nt) {
      float bvv = bias[nt * 32 + c];
      #pragma unroll
      for (int i = 0; i < 16; ++i) acc[nt][i] = bvv;
    }
    #pragma unroll
    for (int kst = 0; kst < 8; ++kst) {
      #pragma unroll
      for (int nt = 0; nt < 4; ++nt) {
        bf16x8 bb = *(const bf16x8*)(wl + (nt * 32 + c) * LDW + kst * 16 + hl * 8);
        acc[nt] = __builtin_amdgcn_mfma_f32_32x32x16_bf16(afrag[kst], bb, acc[nt], 0, 0, 0);
      }
    }
  };

  // C-tile layout: col=lane&31, row=(reg&3)+8*(reg>>2)+4*hl
  auto writeTransposedLDS = [&](f32x16* acc) {   // wl[d][s]
    #pragma unroll
    for (int nt = 0; nt < 4; ++nt) {
      int d = nt * 32 + c;
      #pragma unroll
      for (int g = 0; g < 4; ++g) {
        #pragma unroll
        for (int p = 0; p < 2; ++p) {
          int reg = g * 4 + p * 2;
          int sl  = wv * 32 + g * 8 + hl * 4 + p * 2;
          uint32_t pk = (uint32_t)(uint16_t)f2bf(acc[nt][reg]) |
                        ((uint32_t)(uint16_t)f2bf(acc[nt][reg + 1]) << 16);
          *(uint32_t*)(wl + d * LDW + sl) = pk;
        }
      }
    }
  };

  auto storeTransposed = [&](short* dst) {  // dst [b][d][s]
    #pragma unroll
    for (int it = 0; it < 8; ++it) {
      int l  = it * 256 + tid;
      int d  = l >> 4;
      int s8 = (l & 15) << 3;
      bf16x8 vv = *(const bf16x8*)(wl + d * LDW + s8);
      *(bf16x8*)(dst + ((size_t)b * 128 + d) * S_ + s0 + s8) = vv;
    }
  };

  // ---- Q (row-major out, via LDS for coalesced 16B stores) ----
  stageW(Wq);
  __syncthreads();
  {
    f32x16 acc[4];
    gemm(bq, acc);
    __syncthreads();          // all waves done reading Wq from wl
    #pragma unroll
    for (int nt = 0; nt < 4; ++nt) {
      #pragma unroll
      for (int reg = 0; reg < 16; ++reg) {
        int row = (reg & 3) + 8 * (reg >> 2) + 4 * hl;
        wl[(wv * 32 + row) * LDW + nt * 32 + c] = f2bf(acc[nt][reg]);
      }
    }
    __syncthreads();
    #pragma unroll
    for (int it = 0; it < 8; ++it) {
      int l  = it * 256 + tid;
      int s  = l >> 4;
      int d8 = (l & 15) << 3;
      bf16x8 vv = *(const bf16x8*)(wl + s * LDW + d8);
      *(bf16x8*)(qb + (size_t)(r0 + s) * 128 + d8) = vv;
    }
  }
  __syncthreads();

  // ---- K (transposed out) ----
  stageW(Wk);
  __syncthreads();
  {
    f32x16 acc[4];
    gemm(bk, acc);
    __syncthreads();
    writeTransposedLDS(acc);
    __syncthreads();
    storeTransposed(ktb);
  }
  __syncthreads();

  // ---- V (transposed out) ----
  stageW(Wv);
  __syncthreads();
  {
    f32x16 acc[4];
    gemm(bv, acc);
    __syncthreads();
    writeTransposedLDS(acc);
    __syncthreads();
    storeTransposed(vtb);
  }
}

// ---------------------------------------------------------------------------
// Attention: 256 blocks (b,n) x 512 threads (8 waves).
// Double-buffered chunk loop: prefetch chunk j+1 (global->regs) before MFMAs
// on chunk j; one barrier per chunk. Q frags prefetched during M->LDS phase.
// Out epilogue via per-wave padded LDS patch -> float4 stores.
// ---------------------------------------------------------------------------
#define LDC 72    // chunk tile leading dim (shorts); 144B rows, 16B-aligned
#define LDM 136
#define BUFB 36864   // bytes per (kt+vt) chunk buffer

__global__ __launch_bounds__(512) void attn_kernel(
    const short* __restrict__ qb, const short* __restrict__ ktb,
    const short* __restrict__ vtb, float* __restrict__ out)
{
  // buf0 | buf1 (each kt+vt = 36864 B), opat (8 waves * 32*36 f32 = 36864 B)
  __shared__ __align__(16) char smem[2 * BUFB + BUFB];
  short* m_l  = (short*)smem;                 // alias buf0 (34816 B <= 36864)
  float* opat = (float*)(smem + 2 * BUFB);

  const int tid  = threadIdx.x;
  const int lane = tid & 63;
  const int wv   = tid >> 6;        // 0..7
  const int c    = lane & 31;
  const int hl   = lane >> 5;
  const int b    = blockIdx.x >> 5;
  const int n    = blockIdx.x & 31;

  const int win_lo = (n == 0) ? 0 : n * 256 - 255;
  const int win_hi = (n == 31) ? S_ : n * 256 + 511;
  const int jlo = (n == 0) ? 4 : 0;
  const int jhi = (n == 31) ? 8 : 12;
  const int cbase = n * 256 - 256;

  const short* ktb_b = ktb + (size_t)b * 128 * S_;
  const short* vtb_b = vtb + (size_t)b * 128 * S_;

  const int ht = wv >> 1;           // h-tile (A rows) 0..3
  const int dh = wv & 1;            // d-half (B tiles)

  // staging addressing: 512 thr * 2 iters * 16B covers 128d x 64s per tensor
  const int sd  = tid >> 3;         // d row (it adds 64)
  const int ss8 = (tid & 7) << 3;   // s offset within chunk

  f32x16 macc[2];
  #pragma unroll
  for (int ntl = 0; ntl < 2; ++ntl)
    #pragma unroll
    for (int i = 0; i < 16; ++i) macc[ntl][i] = 0.f;

  auto loadChunk = [&](int c0, bf16x8* pk, bf16x8* pv) {
    #pragma unroll
    for (int it = 0; it < 2; ++it) {
      int d  = sd + it * 64;
      int sb = c0 + ss8;
      pk[it] = *(const bf16x8*)(ktb_b + (size_t)d * S_ + sb);
      pv[it] = *(const bf16x8*)(vtb_b + (size_t)d * S_ + sb);
    }
  };

  auto storeChunk = [&](int c0, short* buf, bf16x8* pk, bf16x8* pv) {
    short* ktc = buf;
    short* vtc = buf + 128 * LDC;
    int sb = c0 + ss8;
    bool edge = (sb < win_lo) || (sb + 7 >= win_hi);
    #pragma unroll
    for (int it = 0; it < 2; ++it) {
      bf16x8 kv = pk[it];
      if (edge) {
        #pragma unroll
        for (int e = 0; e < 8; ++e)
          if (sb + e < win_lo || sb + e >= win_hi) kv[e] = 0;
      }
      int d = sd + it * 64;
      *(bf16x8*)(ktc + d * LDC + ss8) = kv;
      *(bf16x8*)(vtc + d * LDC + ss8) = pv[it];
    }
  };

  auto mfmaChunk = [&](short* buf) {
    short* ktc = buf;
    short* vtc = buf + 128 * LDC;
    #pragma unroll
    for (int kst = 0; kst < 4; ++kst) {
      bf16x8 a = *(const bf16x8*)(vtc + (ht * 32 + c) * LDC + kst * 16 + hl * 8);
      #pragma unroll
      for (int ntl = 0; ntl < 2; ++ntl) {
        int nt = dh * 2 + ntl;
        bf16x8 bb = *(const bf16x8*)(ktc + (nt * 32 + c) * LDC + kst * 16 + hl * 8);
        macc[ntl] = __builtin_amdgcn_mfma_f32_32x32x16_bf16(a, bb, macc[ntl], 0, 0, 0);
      }
    }
  };

  // prologue: stage first chunk
  {
    bf16x8 pk[2], pv[2];
    loadChunk(cbase + jlo * 64, pk, pv);
    storeChunk(cbase + jlo * 64, (short*)smem, pk, pv);
  }
  __syncthreads();

  for (int j = jlo; j < jhi; ++j) {
    short* cur = (short*)(smem + (size_t)(((j - jlo) & 1) ? BUFB : 0));
    short* nxt = (short*)(smem + (size_t)(((j - jlo) & 1) ? 0 : BUFB));
    bf16x8 pk[2], pv[2];
    const bool more = (j + 1 < jhi);
    if (more) loadChunk(cbase + (j + 1) * 64, pk, pv);
    mfmaChunk(cur);
    if (more) storeChunk(cbase + (j + 1) * 64, nxt, pk, pv);
    __syncthreads();
  }

  // prefetch Q A-frags (overlaps the M->LDS phase)
  bf16x8 qf[8];
  {
    const short* q0p = qb + ((size_t)b * S_ + n * 256 + wv * 32 + c) * 128 + hl * 8;
    #pragma unroll
    for (int kst = 0; kst < 8; ++kst) qf[kst] = *(const bf16x8*)(q0p + kst * 16);
  }

  // phase 2: M^T * scale -> bf16 -> m_l (aliases buf0; barrier above protects)
  const float scale = 0.08838834764831845f;   // 1/sqrt(128)
  #pragma unroll
  for (int ntl = 0; ntl < 2; ++ntl) {
    #pragma unroll
    for (int reg = 0; reg < 16; ++reg) {
      int row = (reg & 3) + 8 * (reg >> 2) + 4 * hl;
      m_l[(ht * 32 + row) * LDM + (dh * 2 + ntl) * 32 + c] =
          f2bf(macc[ntl][reg] * scale);
    }
  }
  __syncthreads();

  // phase 3: O = Q * M; wave wv owns 32 q-rows [n*256+32wv, +32)
  f32x16 oacc[4];
  #pragma unroll
  for (int nt = 0; nt < 4; ++nt)
    #pragma unroll
    for (int i = 0; i < 16; ++i) oacc[nt][i] = 0.f;

  #pragma unroll
  for (int kst = 0; kst < 8; ++kst) {
    #pragma unroll
    for (int nt = 0; nt < 4; ++nt) {
      bf16x8 bb = *(const bf16x8*)(m_l + (nt * 32 + c) * LDM + kst * 16 + hl * 8);
      oacc[nt] = __builtin_amdgcn_mfma_f32_32x32x16_bf16(qf[kst], bb, oacc[nt], 0, 0, 0);
    }
  }

  // epilogue: per-wave LDS patch (32x36 f32) -> coalesced float4 stores
  float* patch = opat + wv * (32 * 36);
  float* outb  = out + ((size_t)b * S_ + n * 256 + wv * 32) * 128;
  #pragma unroll
  for (int nt = 0; nt < 4; ++nt) {
    #pragma unroll
    for (int reg = 0; reg < 16; ++reg) {
      int row = (reg & 3) + 8 * (reg >> 2) + 4 * hl;
      patch[row * 36 + c] = oacc[nt][reg];
    }
    #pragma unroll
    for (int p = 0; p < 4; ++p) {
      int row = p * 8 + (lane >> 3);
      float4 vv = *(const float4*)(patch + row * 36 + (lane & 7) * 4);
      *(float4*)(outb + (size_t)row * 128 + nt * 32 + (lane & 7) * 4) = vv;
    }
  }
}

// ---------------------------------------------------------------------------
extern "C" void kernel_launch(void* const* d_in, const int* in_sizes, int n_in,
                              void* d_out, int out_size, void* d_ws, size_t ws_size,
                              hipStream_t stream) {
  const float* x  = (const float*)d_in[0];
  const float* Wq = (const float*)d_in[1];
  const float* bq = (const float*)d_in[2];
  const float* Wk = (const float*)d_in[3];
  const float* bk = (const float*)d_in[4];
  const float* Wv = (const float*)d_in[5];
  const float* bv = (const float*)d_in[6];
  float* out = (float*)d_out;

  const size_t elems = (size_t)B_ * S_ * 128;
  short* qb  = (short*)d_ws;
  short* ktb = qb + elems;
  short* vtb = ktb + elems;

  proj_kernel<<<512, 256, 0, stream>>>(x, Wq, bq, Wk, bk, Wv, bv, qb, ktb, vtb);
  attn_kernel<<<256, 512, 0, stream>>>(qb, ktb, vtb, out);
}